// Round 3
// baseline (399.315 us; speedup 1.0000x reference)
//
#include <hip/hip_runtime.h>
#include <hip/hip_bf16.h>

#define F_IN   128
#define F_OUT  128

// NOTE: harness delivers integer inputs as int32 (per contract: "integer ->
// const int*"), even though the reference uses int64. edge_index layout:
// sources = ei[0..E), destinations = ei[E..2E).

// ---------------------------------------------------------------------------
// Utility: grid-stride zero (hipMemsetAsync avoided inside graph capture).
// ---------------------------------------------------------------------------
__global__ void zero_kernel(int* __restrict__ p, long n) {
    long i = (long)blockIdx.x * blockDim.x + threadIdx.x;
    long stride = (long)gridDim.x * blockDim.x;
    for (; i < n; i += stride) p[i] = 0;
}

// ---------------------------------------------------------------------------
// CSR build: histogram -> in-place 3-kernel exclusive scan -> bucket fill
// ---------------------------------------------------------------------------

__global__ void hist_kernel(const int* __restrict__ src, int* __restrict__ cnt, int E) {
    int e = blockIdx.x * blockDim.x + threadIdx.x;
    if (e < E) atomicAdd(&cnt[src[e]], 1);
}

// Each block sums a 1024-element chunk of cnt -> partials[b]
__global__ __launch_bounds__(256) void chunk_sums_kernel(const int* __restrict__ cnt,
                                                         int* __restrict__ partials, int n) {
    __shared__ int s[256];
    int b = blockIdx.x, t = threadIdx.x;
    int base = b * 1024 + t * 4;
    int sum = 0;
#pragma unroll
    for (int j = 0; j < 4; ++j) {
        int i = base + j;
        if (i < n) sum += cnt[i];
    }
    s[t] = sum;
    __syncthreads();
    for (int d = 128; d > 0; d >>= 1) {
        if (t < d) s[t] += s[t + d];
        __syncthreads();
    }
    if (t == 0) partials[b] = s[0];
}

// Single block: exclusive scan of partials (nch <= 128)
__global__ __launch_bounds__(128) void scan_partials_kernel(const int* __restrict__ partials,
                                                            int* __restrict__ chunk_off, int nch) {
    __shared__ int s[128];
    int t = threadIdx.x;
    s[t] = (t < nch) ? partials[t] : 0;
    __syncthreads();
    for (int d = 1; d < 128; d <<= 1) {
        int val = s[t];
        int add = (t >= d) ? s[t - d] : 0;
        __syncthreads();
        s[t] = val + add;
        __syncthreads();
    }
    if (t < nch) chunk_off[t] = (t > 0) ? s[t - 1] : 0;
}

// Per-chunk exclusive scan + chunk offset; IN-PLACE: off[] holds counts on
// entry, exclusive prefix on exit.
__global__ __launch_bounds__(256) void scan_chunks_kernel(int* __restrict__ off,
                                                          const int* __restrict__ chunk_off,
                                                          int n) {
    __shared__ int s[256];
    int b = blockIdx.x, t = threadIdx.x;
    int base = b * 1024 + t * 4;
    int v[4];
#pragma unroll
    for (int j = 0; j < 4; ++j) {
        int i = base + j;
        v[j] = (i < n) ? off[i] : 0;
    }
    int l1 = v[0], l2 = l1 + v[1], l3 = l2 + v[2], tot = l3 + v[3];
    s[t] = tot;
    __syncthreads();
    for (int d = 1; d < 256; d <<= 1) {
        int val = s[t];
        int add = (t >= d) ? s[t - d] : 0;
        __syncthreads();
        s[t] = val + add;
        __syncthreads();
    }
    int thr_excl = ((t > 0) ? s[t - 1] : 0) + chunk_off[b];
    if (base + 0 < n) off[base + 0] = thr_excl;
    if (base + 1 < n) off[base + 1] = thr_excl + l1;
    if (base + 2 < n) off[base + 2] = thr_excl + l2;
    if (base + 3 < n) off[base + 3] = thr_excl + l3;
}

// Scatter edges into CSR buckets. off[s] atomically advanced; afterwards
// off[s] == end of segment s (start = off[s-1], or 0 for s==0).
__global__ void fill_kernel(const int* __restrict__ ei, int* __restrict__ off,
                            int* __restrict__ dst_sorted, int E) {
    int e = blockIdx.x * blockDim.x + threadIdx.x;
    if (e < E) {
        int s = ei[e];
        int d = ei[E + e];
        int p = atomicAdd(&off[s], 1);
        dst_sorted[p] = d;
    }
}

// ---------------------------------------------------------------------------
// Gather-aggregate into d_out: agg[n][f] = sum_{j in seg(n)} x[dst[j]][f] / deg
// 2 nodes per 256-thread block, 128 threads (one per feature) per node.
// ---------------------------------------------------------------------------
__global__ __launch_bounds__(256) void gather_kernel(const float* __restrict__ x,
                                                     const int* __restrict__ off,
                                                     const int* __restrict__ dst_sorted,
                                                     float* __restrict__ agg, int N) {
    int node = blockIdx.x * 2 + (threadIdx.x >> 7);
    int f = threadIdx.x & 127;
    if (node >= N) return;
    int start = (node == 0) ? 0 : off[node - 1];
    int end = off[node];
    float acc = 0.0f;
    for (int j = start; j < end; ++j) {
        int d = dst_sorted[j];
        acc += x[(long)d * F_IN + f];
    }
    int deg = end - start;
    float scale = (deg > 0) ? (1.0f / (float)deg) : 1.0f;
    agg[(long)node * F_IN + f] = acc * scale;
}

// ---------------------------------------------------------------------------
// Fallback path (small ws): deg -> invdeg, then scaled atomic adds.
// ---------------------------------------------------------------------------
__global__ void invdeg_kernel(int* __restrict__ deg_io, int N) {
    int i = blockIdx.x * blockDim.x + threadIdx.x;
    if (i < N) {
        int d = deg_io[i];
        float inv = (d > 0) ? (1.0f / (float)d) : 1.0f;
        ((float*)deg_io)[i] = inv;
    }
}

__global__ __launch_bounds__(128) void scatter_atomic_kernel(const float* __restrict__ x,
                                                             const int* __restrict__ ei,
                                                             const float* __restrict__ invdeg,
                                                             float* __restrict__ out, int E) {
    int e = blockIdx.x;
    int f = threadIdx.x;
    int s = ei[e];
    int d = ei[E + e];
    float v = x[(long)d * F_IN + f] * invdeg[s];
    atomicAdd(&out[(long)s * F_IN + f], v);
}

// ---------------------------------------------------------------------------
// Fused GEMM: out = agg @ W^T + x @ B^T   (K = 256, 4 chunks of 64)
// agg lives in `out` (in-place; block reads only its own rows, writes after).
// k-major LDS: As[kk][m] (64x68), Ms[kk][c] (64x132). 8x4 thread tile.
// ---------------------------------------------------------------------------
__global__ __launch_bounds__(256) void gemm_fused_kernel(const float* __restrict__ x,
                                                         const float* __restrict__ W,
                                                         const float* __restrict__ Bm,
                                                         float* __restrict__ out, int N) {
    __shared__ float As[64][68];
    __shared__ float Ms[64][132];
    int t = threadIdx.x;
    int row0 = blockIdx.x * 64;
    int c0 = (t & 31) * 4;
    int r0 = (t >> 5) * 8;
    float acc[8][4];
#pragma unroll
    for (int i = 0; i < 8; ++i)
#pragma unroll
        for (int j = 0; j < 4; ++j) acc[i][j] = 0.0f;

    for (int kc = 0; kc < 4; ++kc) {
        const float* Asrc = (kc < 2) ? out : x;
        const float* Msrc = (kc < 2) ? W : Bm;
        int k0 = (kc & 1) * 64;
#pragma unroll
        for (int i = 0; i < 4; ++i) {
            int flat = t + 256 * i;
            int m = flat >> 4, ks = flat & 15;
            int row = row0 + m;
            float4 v = make_float4(0.f, 0.f, 0.f, 0.f);
            if (row < N) v = *(const float4*)&Asrc[(long)row * 128 + k0 + ks * 4];
            As[ks * 4 + 0][m] = v.x;
            As[ks * 4 + 1][m] = v.y;
            As[ks * 4 + 2][m] = v.z;
            As[ks * 4 + 3][m] = v.w;
        }
#pragma unroll
        for (int i = 0; i < 8; ++i) {
            int flat = t + 256 * i;
            int c = flat >> 4, ks = flat & 15;
            float4 v = *(const float4*)&Msrc[(long)c * 128 + k0 + ks * 4];
            Ms[ks * 4 + 0][c] = v.x;
            Ms[ks * 4 + 1][c] = v.y;
            Ms[ks * 4 + 2][c] = v.z;
            Ms[ks * 4 + 3][c] = v.w;
        }
        __syncthreads();
#pragma unroll 8
        for (int kk = 0; kk < 64; ++kk) {
            float4 a0 = *(const float4*)&As[kk][r0];
            float4 a1 = *(const float4*)&As[kk][r0 + 4];
            float4 m0 = *(const float4*)&Ms[kk][c0];
            float a[8] = {a0.x, a0.y, a0.z, a0.w, a1.x, a1.y, a1.z, a1.w};
            float m[4] = {m0.x, m0.y, m0.z, m0.w};
#pragma unroll
            for (int i = 0; i < 8; ++i)
#pragma unroll
                for (int j = 0; j < 4; ++j) acc[i][j] += a[i] * m[j];
        }
        __syncthreads();
    }
#pragma unroll
    for (int i = 0; i < 8; ++i) {
        int row = row0 + r0 + i;
        if (row < N) {
            float4 v = make_float4(acc[i][0], acc[i][1], acc[i][2], acc[i][3]);
            *(float4*)&out[(long)row * 128 + c0] = v;
        }
    }
}

// ---------------------------------------------------------------------------

extern "C" void kernel_launch(void* const* d_in, const int* in_sizes, int n_in,
                              void* d_out, int out_size, void* d_ws, size_t ws_size,
                              hipStream_t stream) {
    const float* x = (const float*)d_in[0];
    const int* ei = (const int*)d_in[1];     // int32 per harness contract
    const float* W = (const float*)d_in[2];
    const float* Bm = (const float*)d_in[3];
    float* out = (float*)d_out;

    const int N = in_sizes[0] / F_IN;   // 100000
    const int E = in_sizes[1] / 2;      // 625000
    const int NCHUNK = (N + 1023) / 1024;

    const size_t need_csr = ((size_t)N + 256 + (size_t)E) * sizeof(int);
    const size_t need_deg = (size_t)N * sizeof(int);

    if (ws_size >= need_csr) {
        // ---------------- CSR + gather path ----------------
        int* off        = (int*)d_ws;        // counts -> exclusive prefix -> ends
        int* partials   = off + N;
        int* chunk_off  = partials + 128;
        int* dst_sorted = chunk_off + 128;

        zero_kernel<<<256, 256, 0, stream>>>(off, N);
        hist_kernel<<<(E + 255) / 256, 256, 0, stream>>>(ei, off, E);
        chunk_sums_kernel<<<NCHUNK, 256, 0, stream>>>(off, partials, N);
        scan_partials_kernel<<<1, 128, 0, stream>>>(partials, chunk_off, NCHUNK);
        scan_chunks_kernel<<<NCHUNK, 256, 0, stream>>>(off, chunk_off, N);
        fill_kernel<<<(E + 255) / 256, 256, 0, stream>>>(ei, off, dst_sorted, E);
        gather_kernel<<<(N + 1) / 2, 256, 0, stream>>>(x, off, dst_sorted, out, N);
    } else if (ws_size >= need_deg) {
        // ---------------- atomic scatter fallback ----------------
        int* deg = (int*)d_ws;
        zero_kernel<<<256, 256, 0, stream>>>(deg, N);
        hist_kernel<<<(E + 255) / 256, 256, 0, stream>>>(ei, deg, E);
        invdeg_kernel<<<(N + 255) / 256, 256, 0, stream>>>(deg, N);
        zero_kernel<<<512, 256, 0, stream>>>((int*)out, (long)N * F_IN);
        scatter_atomic_kernel<<<E, 128, 0, stream>>>(x, ei, (const float*)deg, out, E);
    } else {
        return;  // no usable workspace: fail validation without faulting
    }

    gemm_fused_kernel<<<(N + 63) / 64, 256, 0, stream>>>(x, W, Bm, out, N);
}

// Round 4
// 265.241 us; speedup vs baseline: 1.5055x; 1.5055x over previous
//
#include <hip/hip_runtime.h>

#define F_IN   128
#define F_OUT  128

typedef __attribute__((ext_vector_type(8))) short short8;
typedef __attribute__((ext_vector_type(4))) float floatx4;

__device__ __forceinline__ float bf16u_to_f_lo(unsigned int u) {
    union { unsigned int i; float f; } c; c.i = u << 16; return c.f;
}
__device__ __forceinline__ float bf16u_to_f_hi(unsigned int u) {
    union { unsigned int i; float f; } c; c.i = u & 0xffff0000u; return c.f;
}
__device__ __forceinline__ unsigned short f_to_bf16(float f) {
    union { float f; unsigned int i; } c; c.f = f;
    unsigned int u = c.i;
    u += 0x7fffu + ((u >> 16) & 1u);   // round-to-nearest-even
    return (unsigned short)(u >> 16);
}

// ---------------------------------------------------------------------------
// Utility: grid-stride zero (hipMemsetAsync avoided inside graph capture).
// ---------------------------------------------------------------------------
__global__ void zero_kernel(int* __restrict__ p, long n) {
    long i = (long)blockIdx.x * blockDim.x + threadIdx.x;
    long stride = (long)gridDim.x * blockDim.x;
    for (; i < n; i += stride) p[i] = 0;
}

// ---------------------------------------------------------------------------
// CSR build: histogram -> in-place 3-kernel exclusive scan -> bucket fill
// edge_index arrives as int32 (harness contract): src = ei[0..E), dst = ei[E..2E)
// ---------------------------------------------------------------------------
__global__ void hist_kernel(const int* __restrict__ src, int* __restrict__ cnt, int E) {
    int e = blockIdx.x * blockDim.x + threadIdx.x;
    if (e < E) atomicAdd(&cnt[src[e]], 1);
}

__global__ __launch_bounds__(256) void chunk_sums_kernel(const int* __restrict__ cnt,
                                                         int* __restrict__ partials, int n) {
    __shared__ int s[256];
    int b = blockIdx.x, t = threadIdx.x;
    int base = b * 1024 + t * 4;
    int sum = 0;
#pragma unroll
    for (int j = 0; j < 4; ++j) {
        int i = base + j;
        if (i < n) sum += cnt[i];
    }
    s[t] = sum;
    __syncthreads();
    for (int d = 128; d > 0; d >>= 1) {
        if (t < d) s[t] += s[t + d];
        __syncthreads();
    }
    if (t == 0) partials[b] = s[0];
}

__global__ __launch_bounds__(128) void scan_partials_kernel(const int* __restrict__ partials,
                                                            int* __restrict__ chunk_off, int nch) {
    __shared__ int s[128];
    int t = threadIdx.x;
    s[t] = (t < nch) ? partials[t] : 0;
    __syncthreads();
    for (int d = 1; d < 128; d <<= 1) {
        int val = s[t];
        int add = (t >= d) ? s[t - d] : 0;
        __syncthreads();
        s[t] = val + add;
        __syncthreads();
    }
    if (t < nch) chunk_off[t] = (t > 0) ? s[t - 1] : 0;
}

__global__ __launch_bounds__(256) void scan_chunks_kernel(int* __restrict__ off,
                                                          const int* __restrict__ chunk_off,
                                                          int n) {
    __shared__ int s[256];
    int b = blockIdx.x, t = threadIdx.x;
    int base = b * 1024 + t * 4;
    int v[4];
#pragma unroll
    for (int j = 0; j < 4; ++j) {
        int i = base + j;
        v[j] = (i < n) ? off[i] : 0;
    }
    int l1 = v[0], l2 = l1 + v[1], l3 = l2 + v[2], tot = l3 + v[3];
    s[t] = tot;
    __syncthreads();
    for (int d = 1; d < 256; d <<= 1) {
        int val = s[t];
        int add = (t >= d) ? s[t - d] : 0;
        __syncthreads();
        s[t] = val + add;
        __syncthreads();
    }
    int thr_excl = ((t > 0) ? s[t - 1] : 0) + chunk_off[b];
    if (base + 0 < n) off[base + 0] = thr_excl;
    if (base + 1 < n) off[base + 1] = thr_excl + l1;
    if (base + 2 < n) off[base + 2] = thr_excl + l2;
    if (base + 3 < n) off[base + 3] = thr_excl + l3;
}

__global__ void fill_kernel(const int* __restrict__ ei, int* __restrict__ off,
                            int* __restrict__ dst_sorted, int E) {
    int e = blockIdx.x * blockDim.x + threadIdx.x;
    if (e < E) {
        int s = ei[e];
        int d = ei[E + e];
        int p = atomicAdd(&off[s], 1);
        dst_sorted[p] = d;
    }
}

// ---------------------------------------------------------------------------
// convert x (fp32) -> bf16 packed into out row bytes [256,512)
// thread = (row, seg): reads float4, writes 4 bf16 (8 B).
// ---------------------------------------------------------------------------
__global__ __launch_bounds__(256) void convert_x_kernel(const float* __restrict__ x,
                                                        char* __restrict__ outb, int N) {
    long tid = (long)blockIdx.x * blockDim.x + threadIdx.x;
    if (tid >= (long)N * 32) return;
    int row = (int)(tid >> 5);
    int seg = (int)(tid & 31);
    float4 v = *(const float4*)(x + (size_t)row * 128 + seg * 4);
    unsigned short r[4] = {f_to_bf16(v.x), f_to_bf16(v.y), f_to_bf16(v.z), f_to_bf16(v.w)};
    *(ushort4*)(outb + (size_t)row * 512 + 256 + seg * 8) =
        make_ushort4(r[0], r[1], r[2], r[3]);
}

// convert W,B -> Mb[n][k] bf16, k-major (k<128: W, k>=128: B). 128 blocks x 256.
__global__ __launch_bounds__(256) void convert_M_kernel(const float* __restrict__ W,
                                                        const float* __restrict__ Bm,
                                                        unsigned short* __restrict__ Mb) {
    int n = blockIdx.x;
    int k = threadIdx.x;
    float v = (k < 128) ? W[n * 128 + k] : Bm[n * 128 + (k - 128)];
    Mb[n * 256 + k] = f_to_bf16(v);
}

// ---------------------------------------------------------------------------
// Gather-aggregate (bf16 in / bf16 out, fp32 accumulate):
//   reads x_bf16 from out row bytes [256,512), writes agg_bf16 to bytes [0,256).
// 16 lanes per node (uint4 = 8 bf16 each), 16 nodes per 256-thread block,
// unrolled by 2 for memory-level parallelism.
// ---------------------------------------------------------------------------
__global__ __launch_bounds__(256) void gather_bf16_kernel(const int* __restrict__ off,
                                                          const int* __restrict__ dst_sorted,
                                                          char* __restrict__ outb, int N) {
    int node = blockIdx.x * 16 + (threadIdx.x >> 4);
    int lane = threadIdx.x & 15;
    if (node >= N) return;
    int start = (node == 0) ? 0 : off[node - 1];
    int end = off[node];
    float acc[8];
#pragma unroll
    for (int i = 0; i < 8; ++i) acc[i] = 0.0f;

    const char* xb = outb;  // + d*512 + 256 + lane*16
    int j = start;
    for (; j + 2 <= end; j += 2) {
        int d0 = dst_sorted[j];
        int d1 = dst_sorted[j + 1];
        uint4 a = *(const uint4*)(xb + (size_t)d0 * 512 + 256 + lane * 16);
        uint4 b = *(const uint4*)(xb + (size_t)d1 * 512 + 256 + lane * 16);
        acc[0] += bf16u_to_f_lo(a.x); acc[1] += bf16u_to_f_hi(a.x);
        acc[2] += bf16u_to_f_lo(a.y); acc[3] += bf16u_to_f_hi(a.y);
        acc[4] += bf16u_to_f_lo(a.z); acc[5] += bf16u_to_f_hi(a.z);
        acc[6] += bf16u_to_f_lo(a.w); acc[7] += bf16u_to_f_hi(a.w);
        acc[0] += bf16u_to_f_lo(b.x); acc[1] += bf16u_to_f_hi(b.x);
        acc[2] += bf16u_to_f_lo(b.y); acc[3] += bf16u_to_f_hi(b.y);
        acc[4] += bf16u_to_f_lo(b.z); acc[5] += bf16u_to_f_hi(b.z);
        acc[6] += bf16u_to_f_lo(b.w); acc[7] += bf16u_to_f_hi(b.w);
    }
    if (j < end) {
        int d0 = dst_sorted[j];
        uint4 a = *(const uint4*)(xb + (size_t)d0 * 512 + 256 + lane * 16);
        acc[0] += bf16u_to_f_lo(a.x); acc[1] += bf16u_to_f_hi(a.x);
        acc[2] += bf16u_to_f_lo(a.y); acc[3] += bf16u_to_f_hi(a.y);
        acc[4] += bf16u_to_f_lo(a.z); acc[5] += bf16u_to_f_hi(a.z);
        acc[6] += bf16u_to_f_lo(a.w); acc[7] += bf16u_to_f_hi(a.w);
    }
    int deg = end - start;
    float scale = (deg > 0) ? (1.0f / (float)deg) : 1.0f;
    unsigned short r[8];
#pragma unroll
    for (int i = 0; i < 8; ++i) r[i] = f_to_bf16(acc[i] * scale);
    uint4 pk;
    pk.x = (unsigned int)r[0] | ((unsigned int)r[1] << 16);
    pk.y = (unsigned int)r[2] | ((unsigned int)r[3] << 16);
    pk.z = (unsigned int)r[4] | ((unsigned int)r[5] << 16);
    pk.w = (unsigned int)r[6] | ((unsigned int)r[7] << 16);
    *(uint4*)(outb + (size_t)node * 512 + lane * 16) = pk;
}

// ---------------------------------------------------------------------------
// MFMA GEMM: out[m][n] = sum_k A[m][k] * Mb[n][k], A = bf16 [agg|x] packed in
// out rows (K=256), Mb = bf16 [128][256]. 4 waves/block, wave = 16 rows x 128
// cols, mfma_f32_16x16x32_bf16, A-frags register-resident, no LDS.
// In-place: each wave reads only its own 16 rows before storing them.
// ---------------------------------------------------------------------------
__global__ __launch_bounds__(256) void gemm_mfma_kernel(const unsigned short* __restrict__ Mb,
                                                        float* __restrict__ out, int N) {
    int w = threadIdx.x >> 6;
    int lane = threadIdx.x & 63;
    int m16 = lane & 15;
    int quad = lane >> 4;
    int rowbase = blockIdx.x * 64 + w * 16;

    int arow = rowbase + m16;
    if (arow > N - 1) arow = N - 1;  // clamp: loads stay in-bounds, stores guarded
    const char* ab = (const char*)out + (size_t)arow * 512;

    short8 afrag[8];
#pragma unroll
    for (int s = 0; s < 8; ++s)
        afrag[s] = *(const short8*)(ab + s * 64 + quad * 16);

    floatx4 acc[8];
#pragma unroll
    for (int nt = 0; nt < 8; ++nt) acc[nt] = (floatx4){0.f, 0.f, 0.f, 0.f};

#pragma unroll
    for (int nt = 0; nt < 8; ++nt) {
        const char* bb = (const char*)(Mb + (size_t)(nt * 16 + m16) * 256);
#pragma unroll
        for (int s = 0; s < 8; ++s) {
            short8 bfrag = *(const short8*)(bb + s * 64 + quad * 16);
            acc[nt] = __builtin_amdgcn_mfma_f32_16x16x32_bf16(afrag[s], bfrag, acc[nt], 0, 0, 0);
        }
    }

#pragma unroll
    for (int nt = 0; nt < 8; ++nt) {
#pragma unroll
        for (int r = 0; r < 4; ++r) {
            int gr = rowbase + quad * 4 + r;
            if (gr < N) out[(size_t)gr * 128 + nt * 16 + m16] = acc[nt][r];
        }
    }
}

// ---------------------------------------------------------------------------
// Fallback kernels (fp32 paths) — unchanged from the passing round.
// ---------------------------------------------------------------------------
__global__ __launch_bounds__(256) void gather_kernel(const float* __restrict__ x,
                                                     const int* __restrict__ off,
                                                     const int* __restrict__ dst_sorted,
                                                     float* __restrict__ agg, int N) {
    int node = blockIdx.x * 2 + (threadIdx.x >> 7);
    int f = threadIdx.x & 127;
    if (node >= N) return;
    int start = (node == 0) ? 0 : off[node - 1];
    int end = off[node];
    float acc = 0.0f;
    for (int j = start; j < end; ++j) {
        int d = dst_sorted[j];
        acc += x[(long)d * F_IN + f];
    }
    int deg = end - start;
    float scale = (deg > 0) ? (1.0f / (float)deg) : 1.0f;
    agg[(long)node * F_IN + f] = acc * scale;
}

__global__ void invdeg_kernel(int* __restrict__ deg_io, int N) {
    int i = blockIdx.x * blockDim.x + threadIdx.x;
    if (i < N) {
        int d = deg_io[i];
        float inv = (d > 0) ? (1.0f / (float)d) : 1.0f;
        ((float*)deg_io)[i] = inv;
    }
}

__global__ __launch_bounds__(128) void scatter_atomic_kernel(const float* __restrict__ x,
                                                             const int* __restrict__ ei,
                                                             const float* __restrict__ invdeg,
                                                             float* __restrict__ out, int E) {
    int e = blockIdx.x;
    int f = threadIdx.x;
    int s = ei[e];
    int d = ei[E + e];
    float v = x[(long)d * F_IN + f] * invdeg[s];
    atomicAdd(&out[(long)s * F_IN + f], v);
}

__global__ __launch_bounds__(256) void gemm_fused_kernel(const float* __restrict__ x,
                                                         const float* __restrict__ W,
                                                         const float* __restrict__ Bm,
                                                         float* __restrict__ out, int N) {
    __shared__ float As[64][68];
    __shared__ float Ms[64][132];
    int t = threadIdx.x;
    int row0 = blockIdx.x * 64;
    int c0 = (t & 31) * 4;
    int r0 = (t >> 5) * 8;
    float acc[8][4];
#pragma unroll
    for (int i = 0; i < 8; ++i)
#pragma unroll
        for (int j = 0; j < 4; ++j) acc[i][j] = 0.0f;

    for (int kc = 0; kc < 4; ++kc) {
        const float* Asrc = (kc < 2) ? out : x;
        const float* Msrc = (kc < 2) ? W : Bm;
        int k0 = (kc & 1) * 64;
#pragma unroll
        for (int i = 0; i < 4; ++i) {
            int flat = t + 256 * i;
            int m = flat >> 4, ks = flat & 15;
            int row = row0 + m;
            float4 v = make_float4(0.f, 0.f, 0.f, 0.f);
            if (row < N) v = *(const float4*)&Asrc[(long)row * 128 + k0 + ks * 4];
            As[ks * 4 + 0][m] = v.x;
            As[ks * 4 + 1][m] = v.y;
            As[ks * 4 + 2][m] = v.z;
            As[ks * 4 + 3][m] = v.w;
        }
#pragma unroll
        for (int i = 0; i < 8; ++i) {
            int flat = t + 256 * i;
            int c = flat >> 4, ks = flat & 15;
            float4 v = *(const float4*)&Msrc[(long)c * 128 + k0 + ks * 4];
            Ms[ks * 4 + 0][c] = v.x;
            Ms[ks * 4 + 1][c] = v.y;
            Ms[ks * 4 + 2][c] = v.z;
            Ms[ks * 4 + 3][c] = v.w;
        }
        __syncthreads();
#pragma unroll 8
        for (int kk = 0; kk < 64; ++kk) {
            float4 a0 = *(const float4*)&As[kk][r0];
            float4 a1 = *(const float4*)&As[kk][r0 + 4];
            float4 m0 = *(const float4*)&Ms[kk][c0];
            float a[8] = {a0.x, a0.y, a0.z, a0.w, a1.x, a1.y, a1.z, a1.w};
            float m[4] = {m0.x, m0.y, m0.z, m0.w};
#pragma unroll
            for (int i = 0; i < 8; ++i)
#pragma unroll
                for (int j = 0; j < 4; ++j) acc[i][j] += a[i] * m[j];
        }
        __syncthreads();
    }
#pragma unroll
    for (int i = 0; i < 8; ++i) {
        int row = row0 + r0 + i;
        if (row < N) {
            float4 v = make_float4(acc[i][0], acc[i][1], acc[i][2], acc[i][3]);
            *(float4*)&out[(long)row * 128 + c0] = v;
        }
    }
}

// ---------------------------------------------------------------------------

extern "C" void kernel_launch(void* const* d_in, const int* in_sizes, int n_in,
                              void* d_out, int out_size, void* d_ws, size_t ws_size,
                              hipStream_t stream) {
    const float* x = (const float*)d_in[0];
    const int* ei = (const int*)d_in[1];     // int32 per harness contract
    const float* W = (const float*)d_in[2];
    const float* Bm = (const float*)d_in[3];
    float* out = (float*)d_out;

    const int N = in_sizes[0] / F_IN;   // 100000
    const int E = in_sizes[1] / 2;      // 625000
    const int NCHUNK = (N + 1023) / 1024;

    // ws layout: off[N], partials[128], chunk_off[128], dst_sorted[E], Mb[128*256 bf16]
    int* off        = (int*)d_ws;
    int* partials   = off + N;
    int* chunk_off  = partials + 128;
    int* dst_sorted = chunk_off + 128;
    size_t mb_off   = (((size_t)(N + 256 + E) * sizeof(int)) + 15) & ~(size_t)15;
    unsigned short* Mb = (unsigned short*)((char*)d_ws + mb_off);

    const size_t need_bf16 = mb_off + (size_t)128 * 256 * sizeof(unsigned short);
    const size_t need_csr  = ((size_t)N + 256 + (size_t)E) * sizeof(int);
    const size_t need_deg  = (size_t)N * sizeof(int);

    if (ws_size >= need_bf16) {
        // -------- primary path: CSR + bf16 gather + MFMA GEMM --------
        zero_kernel<<<256, 256, 0, stream>>>(off, N);
        hist_kernel<<<(E + 255) / 256, 256, 0, stream>>>(ei, off, E);
        chunk_sums_kernel<<<NCHUNK, 256, 0, stream>>>(off, partials, N);
        scan_partials_kernel<<<1, 128, 0, stream>>>(partials, chunk_off, NCHUNK);
        scan_chunks_kernel<<<NCHUNK, 256, 0, stream>>>(off, chunk_off, N);
        fill_kernel<<<(E + 255) / 256, 256, 0, stream>>>(ei, off, dst_sorted, E);
        convert_M_kernel<<<128, 256, 0, stream>>>(W, Bm, Mb);
        {
            long tot = (long)N * 32;
            convert_x_kernel<<<(int)((tot + 255) / 256), 256, 0, stream>>>(x, (char*)out, N);
        }
        gather_bf16_kernel<<<(N + 15) / 16, 256, 0, stream>>>(off, dst_sorted, (char*)out, N);
        gemm_mfma_kernel<<<(N + 63) / 64, 256, 0, stream>>>(Mb, out, N);
    } else if (ws_size >= need_csr) {
        // -------- fp32 CSR fallback --------
        zero_kernel<<<256, 256, 0, stream>>>(off, N);
        hist_kernel<<<(E + 255) / 256, 256, 0, stream>>>(ei, off, E);
        chunk_sums_kernel<<<NCHUNK, 256, 0, stream>>>(off, partials, N);
        scan_partials_kernel<<<1, 128, 0, stream>>>(partials, chunk_off, NCHUNK);
        scan_chunks_kernel<<<NCHUNK, 256, 0, stream>>>(off, chunk_off, N);
        fill_kernel<<<(E + 255) / 256, 256, 0, stream>>>(ei, off, dst_sorted, E);
        gather_kernel<<<(N + 1) / 2, 256, 0, stream>>>(x, off, dst_sorted, out, N);
        gemm_fused_kernel<<<(N + 63) / 64, 256, 0, stream>>>(x, W, Bm, out, N);
    } else if (ws_size >= need_deg) {
        // -------- atomic scatter fallback --------
        int* deg = (int*)d_ws;
        zero_kernel<<<256, 256, 0, stream>>>(deg, N);
        hist_kernel<<<(E + 255) / 256, 256, 0, stream>>>(ei, deg, E);
        invdeg_kernel<<<(N + 255) / 256, 256, 0, stream>>>(deg, N);
        zero_kernel<<<512, 256, 0, stream>>>((int*)out, (long)N * F_IN);
        scatter_atomic_kernel<<<E, 128, 0, stream>>>(x, ei, (const float*)deg, out, E);
        gemm_fused_kernel<<<(N + 63) / 64, 256, 0, stream>>>(x, W, Bm, out, N);
    }
}

// Round 5
// 232.783 us; speedup vs baseline: 1.7154x; 1.1394x over previous
//
#include <hip/hip_runtime.h>

#define F_IN   128
#define F_OUT  128

typedef __attribute__((ext_vector_type(8))) short short8;
typedef __attribute__((ext_vector_type(4))) float floatx4;

__device__ __forceinline__ float bf16u_to_f_lo(unsigned int u) {
    union { unsigned int i; float f; } c; c.i = u << 16; return c.f;
}
__device__ __forceinline__ float bf16u_to_f_hi(unsigned int u) {
    union { unsigned int i; float f; } c; c.i = u & 0xffff0000u; return c.f;
}
__device__ __forceinline__ unsigned short f_to_bf16(float f) {
    union { float f; unsigned int i; } c; c.f = f;
    unsigned int u = c.i;
    u += 0x7fffu + ((u >> 16) & 1u);   // round-to-nearest-even
    return (unsigned short)(u >> 16);
}
__device__ __forceinline__ unsigned int pack2(unsigned short a, unsigned short b) {
    return (unsigned int)a | ((unsigned int)b << 16);
}

// ---------------------------------------------------------------------------
__global__ void zero_kernel(int* __restrict__ p, long n) {
    long i = (long)blockIdx.x * blockDim.x + threadIdx.x;
    long stride = (long)gridDim.x * blockDim.x;
    for (; i < n; i += stride) p[i] = 0;
}

// ---------------------------------------------------------------------------
// CSR build. edge_index arrives int32: src = ei[0..E), dst = ei[E..2E).
// ---------------------------------------------------------------------------
__global__ void hist_kernel(const int* __restrict__ src, int* __restrict__ cnt, int E) {
    int e = blockIdx.x * blockDim.x + threadIdx.x;
    if (e < E) atomicAdd(&cnt[src[e]], 1);
}

__global__ __launch_bounds__(256) void chunk_sums_kernel(const int* __restrict__ cnt,
                                                         int* __restrict__ partials, int n) {
    __shared__ int s[256];
    int b = blockIdx.x, t = threadIdx.x;
    int base = b * 1024 + t * 4;
    int sum = 0;
#pragma unroll
    for (int j = 0; j < 4; ++j) {
        int i = base + j;
        if (i < n) sum += cnt[i];
    }
    s[t] = sum;
    __syncthreads();
    for (int d = 128; d > 0; d >>= 1) {
        if (t < d) s[t] += s[t + d];
        __syncthreads();
    }
    if (t == 0) partials[b] = s[0];
}

__global__ __launch_bounds__(128) void scan_partials_kernel(const int* __restrict__ partials,
                                                            int* __restrict__ chunk_off, int nch) {
    __shared__ int s[128];
    int t = threadIdx.x;
    s[t] = (t < nch) ? partials[t] : 0;
    __syncthreads();
    for (int d = 1; d < 128; d <<= 1) {
        int val = s[t];
        int add = (t >= d) ? s[t - d] : 0;
        __syncthreads();
        s[t] = val + add;
        __syncthreads();
    }
    if (t < nch) chunk_off[t] = (t > 0) ? s[t - 1] : 0;
}

__global__ __launch_bounds__(256) void scan_chunks_kernel(int* __restrict__ off,
                                                          const int* __restrict__ chunk_off,
                                                          int n) {
    __shared__ int s[256];
    int b = blockIdx.x, t = threadIdx.x;
    int base = b * 1024 + t * 4;
    int v[4];
#pragma unroll
    for (int j = 0; j < 4; ++j) {
        int i = base + j;
        v[j] = (i < n) ? off[i] : 0;
    }
    int l1 = v[0], l2 = l1 + v[1], l3 = l2 + v[2], tot = l3 + v[3];
    s[t] = tot;
    __syncthreads();
    for (int d = 1; d < 256; d <<= 1) {
        int val = s[t];
        int add = (t >= d) ? s[t - d] : 0;
        __syncthreads();
        s[t] = val + add;
        __syncthreads();
    }
    int thr_excl = ((t > 0) ? s[t - 1] : 0) + chunk_off[b];
    if (base + 0 < n) off[base + 0] = thr_excl;
    if (base + 1 < n) off[base + 1] = thr_excl + l1;
    if (base + 2 < n) off[base + 2] = thr_excl + l2;
    if (base + 3 < n) off[base + 3] = thr_excl + l3;
}

__global__ void fill_kernel(const int* __restrict__ ei, int* __restrict__ off,
                            int* __restrict__ dst_sorted, int E) {
    int e = blockIdx.x * blockDim.x + threadIdx.x;
    if (e < E) {
        int s = ei[e];
        int d = ei[E + e];
        int p = atomicAdd(&off[s], 1);
        dst_sorted[p] = d;
    }
}

// ---------------------------------------------------------------------------
// convert x (fp32) -> bf16 packed into out row bytes [256,512)
// ---------------------------------------------------------------------------
__global__ __launch_bounds__(256) void convert_x_kernel(const float* __restrict__ x,
                                                        char* __restrict__ outb, int N) {
    long tid = (long)blockIdx.x * blockDim.x + threadIdx.x;
    if (tid >= (long)N * 32) return;
    int row = (int)(tid >> 5);
    int seg = (int)(tid & 31);
    float4 v = *(const float4*)(x + (size_t)row * 128 + seg * 4);
    unsigned short r[4] = {f_to_bf16(v.x), f_to_bf16(v.y), f_to_bf16(v.z), f_to_bf16(v.w)};
    *(ushort4*)(outb + (size_t)row * 512 + 256 + seg * 8) =
        make_ushort4(r[0], r[1], r[2], r[3]);
}

// ---------------------------------------------------------------------------
// Gather-aggregate (bf16 in/out, fp32 accumulate). 16 lanes/node, uint4 per
// lane per edge, unrolled by 4 for memory-level parallelism.
// ---------------------------------------------------------------------------
__global__ __launch_bounds__(256) void gather_bf16_kernel(const int* __restrict__ off,
                                                          const int* __restrict__ dst_sorted,
                                                          char* __restrict__ outb, int N) {
    int node = blockIdx.x * 16 + (threadIdx.x >> 4);
    int lane = threadIdx.x & 15;
    if (node >= N) return;
    int start = (node == 0) ? 0 : off[node - 1];
    int end = off[node];
    float acc[8];
#pragma unroll
    for (int i = 0; i < 8; ++i) acc[i] = 0.0f;

    const char* xb = outb;
    int j = start;
    for (; j + 4 <= end; j += 4) {
        int d0 = dst_sorted[j];
        int d1 = dst_sorted[j + 1];
        int d2 = dst_sorted[j + 2];
        int d3 = dst_sorted[j + 3];
        uint4 a = *(const uint4*)(xb + (size_t)d0 * 512 + 256 + lane * 16);
        uint4 b = *(const uint4*)(xb + (size_t)d1 * 512 + 256 + lane * 16);
        uint4 c = *(const uint4*)(xb + (size_t)d2 * 512 + 256 + lane * 16);
        uint4 d = *(const uint4*)(xb + (size_t)d3 * 512 + 256 + lane * 16);
        acc[0] += bf16u_to_f_lo(a.x); acc[1] += bf16u_to_f_hi(a.x);
        acc[2] += bf16u_to_f_lo(a.y); acc[3] += bf16u_to_f_hi(a.y);
        acc[4] += bf16u_to_f_lo(a.z); acc[5] += bf16u_to_f_hi(a.z);
        acc[6] += bf16u_to_f_lo(a.w); acc[7] += bf16u_to_f_hi(a.w);
        acc[0] += bf16u_to_f_lo(b.x); acc[1] += bf16u_to_f_hi(b.x);
        acc[2] += bf16u_to_f_lo(b.y); acc[3] += bf16u_to_f_hi(b.y);
        acc[4] += bf16u_to_f_lo(b.z); acc[5] += bf16u_to_f_hi(b.z);
        acc[6] += bf16u_to_f_lo(b.w); acc[7] += bf16u_to_f_hi(b.w);
        acc[0] += bf16u_to_f_lo(c.x); acc[1] += bf16u_to_f_hi(c.x);
        acc[2] += bf16u_to_f_lo(c.y); acc[3] += bf16u_to_f_hi(c.y);
        acc[4] += bf16u_to_f_lo(c.z); acc[5] += bf16u_to_f_hi(c.z);
        acc[6] += bf16u_to_f_lo(c.w); acc[7] += bf16u_to_f_hi(c.w);
        acc[0] += bf16u_to_f_lo(d.x); acc[1] += bf16u_to_f_hi(d.x);
        acc[2] += bf16u_to_f_lo(d.y); acc[3] += bf16u_to_f_hi(d.y);
        acc[4] += bf16u_to_f_lo(d.z); acc[5] += bf16u_to_f_hi(d.z);
        acc[6] += bf16u_to_f_lo(d.w); acc[7] += bf16u_to_f_hi(d.w);
    }
    for (; j < end; ++j) {
        int d0 = dst_sorted[j];
        uint4 a = *(const uint4*)(xb + (size_t)d0 * 512 + 256 + lane * 16);
        acc[0] += bf16u_to_f_lo(a.x); acc[1] += bf16u_to_f_hi(a.x);
        acc[2] += bf16u_to_f_lo(a.y); acc[3] += bf16u_to_f_hi(a.y);
        acc[4] += bf16u_to_f_lo(a.z); acc[5] += bf16u_to_f_hi(a.z);
        acc[6] += bf16u_to_f_lo(a.w); acc[7] += bf16u_to_f_hi(a.w);
    }
    int deg = end - start;
    float scale = (deg > 0) ? (1.0f / (float)deg) : 1.0f;
    unsigned short r[8];
#pragma unroll
    for (int i = 0; i < 8; ++i) r[i] = f_to_bf16(acc[i] * scale);
    uint4 pk;
    pk.x = pack2(r[0], r[1]);
    pk.y = pack2(r[2], r[3]);
    pk.z = pack2(r[4], r[5]);
    pk.w = pack2(r[6], r[7]);
    *(uint4*)(outb + (size_t)node * 512 + lane * 16) = pk;
}

// ---------------------------------------------------------------------------
// MFMA GEMM: out[m][n] = sum_k A[m][k]*M[n][k], A = bf16 [agg|x] in out rows
// (K=256), M = [W;B] converted to bf16 in-kernel. B-fragments staged in LDS in
// exact frag-lane order (conflict-free ds_read_b128). 4 waves/block, each wave
// 32 rows x 128 cols (two 16-row groups sharing B frags). 128 rows/block.
// In-place: each wave reads only its own rows before storing them.
// ---------------------------------------------------------------------------
__global__ __launch_bounds__(256) void gemm_mfma_kernel(const float* __restrict__ W,
                                                        const float* __restrict__ Bm,
                                                        float* __restrict__ out, int N) {
    __shared__ uint4 Bs[4096];  // 64 KB: Bs[(nt*8+s)*64 + lane] = 16B B-frag
    int t = threadIdx.x;
    int lane = t & 63;
    int w = t >> 6;
    int m16 = lane & 15;
    int quad = lane >> 4;

    // ---- stage B: convert fp32 W/B -> bf16 frags, frag-lane-major in LDS ----
#pragma unroll
    for (int nt2 = 0; nt2 < 2; ++nt2) {
        int nt = w * 2 + nt2;
        int n = nt * 16 + m16;
#pragma unroll
        for (int s = 0; s < 8; ++s) {
            int kbase = s * 32 + quad * 8;  // multiple of 8; chunk stays in W or Bm
            const float* srcp = (kbase < 128) ? (W + n * 128 + kbase)
                                              : (Bm + n * 128 + (kbase - 128));
            float4 v0 = *(const float4*)srcp;
            float4 v1 = *(const float4*)(srcp + 4);
            uint4 pk;
            pk.x = pack2(f_to_bf16(v0.x), f_to_bf16(v0.y));
            pk.y = pack2(f_to_bf16(v0.z), f_to_bf16(v0.w));
            pk.z = pack2(f_to_bf16(v1.x), f_to_bf16(v1.y));
            pk.w = pack2(f_to_bf16(v1.z), f_to_bf16(v1.w));
            Bs[(nt * 8 + s) * 64 + lane] = pk;
        }
    }
    __syncthreads();

    // ---- A fragments: 2 row-groups of 16, register-resident ----
    int rowbase = blockIdx.x * 128 + w * 32;
    short8 afrag[2][8];
#pragma unroll
    for (int g = 0; g < 2; ++g) {
        int arow = rowbase + g * 16 + m16;
        if (arow > N - 1) arow = N - 1;  // clamp; NaN only pollutes discarded rows
        const char* ab = (const char*)out + (size_t)arow * 512;
#pragma unroll
        for (int s = 0; s < 8; ++s)
            afrag[g][s] = *(const short8*)(ab + s * 64 + quad * 16);
    }

    floatx4 acc[2][8];
#pragma unroll
    for (int g = 0; g < 2; ++g)
#pragma unroll
        for (int nt = 0; nt < 8; ++nt) acc[g][nt] = (floatx4){0.f, 0.f, 0.f, 0.f};

#pragma unroll
    for (int nt = 0; nt < 8; ++nt) {
#pragma unroll
        for (int s = 0; s < 8; ++s) {
            short8 bfrag = *(const short8*)&Bs[(nt * 8 + s) * 64 + lane];
            acc[0][nt] = __builtin_amdgcn_mfma_f32_16x16x32_bf16(afrag[0][s], bfrag, acc[0][nt], 0, 0, 0);
            acc[1][nt] = __builtin_amdgcn_mfma_f32_16x16x32_bf16(afrag[1][s], bfrag, acc[1][nt], 0, 0, 0);
        }
    }

#pragma unroll
    for (int g = 0; g < 2; ++g)
#pragma unroll
        for (int nt = 0; nt < 8; ++nt)
#pragma unroll
            for (int r = 0; r < 4; ++r) {
                int gr = rowbase + g * 16 + quad * 4 + r;
                if (gr < N) out[(size_t)gr * 128 + nt * 16 + m16] = acc[g][nt][r];
            }
}

// ---------------------------------------------------------------------------
// Atomic-scatter fallback (tiny ws).
// ---------------------------------------------------------------------------
__global__ void invdeg_kernel(int* __restrict__ deg_io, int N) {
    int i = blockIdx.x * blockDim.x + threadIdx.x;
    if (i < N) {
        int d = deg_io[i];
        float inv = (d > 0) ? (1.0f / (float)d) : 1.0f;
        ((float*)deg_io)[i] = inv;
    }
}

__global__ __launch_bounds__(128) void scatter_atomic_kernel(const float* __restrict__ x,
                                                             const int* __restrict__ ei,
                                                             const float* __restrict__ invdeg,
                                                             float* __restrict__ out, int E) {
    int e = blockIdx.x;
    int f = threadIdx.x;
    int s = ei[e];
    int d = ei[E + e];
    float v = x[(long)d * F_IN + f] * invdeg[s];
    atomicAdd(&out[(long)s * F_IN + f], v);
}

__global__ __launch_bounds__(256) void gemm_fused_kernel(const float* __restrict__ x,
                                                         const float* __restrict__ W,
                                                         const float* __restrict__ Bm,
                                                         float* __restrict__ out, int N) {
    __shared__ float As[64][68];
    __shared__ float Ms[64][132];
    int t = threadIdx.x;
    int row0 = blockIdx.x * 64;
    int c0 = (t & 31) * 4;
    int r0 = (t >> 5) * 8;
    float acc[8][4];
#pragma unroll
    for (int i = 0; i < 8; ++i)
#pragma unroll
        for (int j = 0; j < 4; ++j) acc[i][j] = 0.0f;

    for (int kc = 0; kc < 4; ++kc) {
        const float* Asrc = (kc < 2) ? out : x;
        const float* Msrc = (kc < 2) ? W : Bm;
        int k0 = (kc & 1) * 64;
#pragma unroll
        for (int i = 0; i < 4; ++i) {
            int flat = t + 256 * i;
            int m = flat >> 4, ks = flat & 15;
            int row = row0 + m;
            float4 v = make_float4(0.f, 0.f, 0.f, 0.f);
            if (row < N) v = *(const float4*)&Asrc[(long)row * 128 + k0 + ks * 4];
            As[ks * 4 + 0][m] = v.x;
            As[ks * 4 + 1][m] = v.y;
            As[ks * 4 + 2][m] = v.z;
            As[ks * 4 + 3][m] = v.w;
        }
#pragma unroll
        for (int i = 0; i < 8; ++i) {
            int flat = t + 256 * i;
            int c = flat >> 4, ks = flat & 15;
            float4 v = *(const float4*)&Msrc[(long)c * 128 + k0 + ks * 4];
            Ms[ks * 4 + 0][c] = v.x;
            Ms[ks * 4 + 1][c] = v.y;
            Ms[ks * 4 + 2][c] = v.z;
            Ms[ks * 4 + 3][c] = v.w;
        }
        __syncthreads();
#pragma unroll 8
        for (int kk = 0; kk < 64; ++kk) {
            float4 a0 = *(const float4*)&As[kk][r0];
            float4 a1 = *(const float4*)&As[kk][r0 + 4];
            float4 m0 = *(const float4*)&Ms[kk][c0];
            float a[8] = {a0.x, a0.y, a0.z, a0.w, a1.x, a1.y, a1.z, a1.w};
            float m[4] = {m0.x, m0.y, m0.z, m0.w};
#pragma unroll
            for (int i = 0; i < 8; ++i)
#pragma unroll
                for (int j = 0; j < 4; ++j) acc[i][j] += a[i] * m[j];
        }
        __syncthreads();
    }
#pragma unroll
    for (int i = 0; i < 8; ++i) {
        int row = row0 + r0 + i;
        if (row < N) {
            float4 v = make_float4(acc[i][0], acc[i][1], acc[i][2], acc[i][3]);
            *(float4*)&out[(long)row * 128 + c0] = v;
        }
    }
}

// ---------------------------------------------------------------------------

extern "C" void kernel_launch(void* const* d_in, const int* in_sizes, int n_in,
                              void* d_out, int out_size, void* d_ws, size_t ws_size,
                              hipStream_t stream) {
    const float* x = (const float*)d_in[0];
    const int* ei = (const int*)d_in[1];     // int32 per harness contract
    const float* W = (const float*)d_in[2];
    const float* Bm = (const float*)d_in[3];
    float* out = (float*)d_out;

    const int N = in_sizes[0] / F_IN;   // 100000
    const int E = in_sizes[1] / 2;      // 625000
    const int NCHUNK = (N + 1023) / 1024;

    // ws layout: off[N], partials[128], chunk_off[128], dst_sorted[E]
    int* off        = (int*)d_ws;
    int* partials   = off + N;
    int* chunk_off  = partials + 128;
    int* dst_sorted = chunk_off + 128;

    const size_t need_csr = ((size_t)N + 256 + (size_t)E) * sizeof(int);
    const size_t need_deg = (size_t)N * sizeof(int);

    if (ws_size >= need_csr) {
        // -------- primary path: CSR + bf16 gather + LDS-staged MFMA GEMM ----
        zero_kernel<<<256, 256, 0, stream>>>(off, N);
        hist_kernel<<<(E + 255) / 256, 256, 0, stream>>>(ei, off, E);
        chunk_sums_kernel<<<NCHUNK, 256, 0, stream>>>(off, partials, N);
        scan_partials_kernel<<<1, 128, 0, stream>>>(partials, chunk_off, NCHUNK);
        scan_chunks_kernel<<<NCHUNK, 256, 0, stream>>>(off, chunk_off, N);
        fill_kernel<<<(E + 255) / 256, 256, 0, stream>>>(ei, off, dst_sorted, E);
        {
            long tot = (long)N * 32;
            convert_x_kernel<<<(int)((tot + 255) / 256), 256, 0, stream>>>(x, (char*)out, N);
        }
        gather_bf16_kernel<<<(N + 15) / 16, 256, 0, stream>>>(off, dst_sorted, (char*)out, N);
        gemm_mfma_kernel<<<(N + 127) / 128, 256, 0, stream>>>(W, Bm, out, N);
    } else if (ws_size >= need_deg) {
        // -------- atomic scatter fallback --------
        int* deg = (int*)d_ws;
        zero_kernel<<<256, 256, 0, stream>>>(deg, N);
        hist_kernel<<<(E + 255) / 256, 256, 0, stream>>>(ei, deg, E);
        invdeg_kernel<<<(N + 255) / 256, 256, 0, stream>>>(deg, N);
        zero_kernel<<<512, 256, 0, stream>>>((int*)out, (long)N * F_IN);
        scatter_atomic_kernel<<<E, 128, 0, stream>>>(x, ei, (const float*)deg, out, E);
        gemm_fused_kernel<<<(N + 63) / 64, 256, 0, stream>>>(x, W, Bm, out, N);
    }
}